// Round 14
// baseline (356.788 us; speedup 1.0000x reference)
//
#include <hip/hip_runtime.h>

// Problem constants (fixed by the reference)
#define HID 256
#define INC 128
#define OUTC 128

typedef __attribute__((ext_vector_type(8))) short short8;     // 8 bf16 = 4 VGPRs (MFMA A/B frag)
typedef __attribute__((ext_vector_type(4))) float floatx4;    // MFMA C/D frag

__device__ __forceinline__ unsigned short f2bf(float f) {
    unsigned int u = __float_as_uint(f);
    unsigned int r = (u + 0x7FFFu + ((u >> 16) & 1u)) >> 16;  // RNE
    return (unsigned short)r;
}

__device__ __forceinline__ void bfacc2(float* a, uint u, float nr) {
    a[0] = fmaf(nr, __uint_as_float(u << 16), a[0]);
    a[1] = fmaf(nr, __uint_as_float(u & 0xFFFF0000u), a[1]);
}

// ---------------- CSR build ----------------
__global__ void k_hist(const int* __restrict__ dst, int* __restrict__ cnt, int e) {
    int i = blockIdx.x * blockDim.x + threadIdx.x;
    if (i < e) atomicAdd(&cnt[dst[i]], 1);
}

// Local scan (per 256-block) + dinv computed from pre-scan counts (fused).
__global__ __launch_bounds__(256) void k_scan_local(const int* __restrict__ cnt,
                                                    int* __restrict__ ex, int* __restrict__ blk_sum,
                                                    float* __restrict__ dinv, int n) {
    __shared__ int s[256];
    const int t = threadIdx.x;
    const int i = blockIdx.x * 256 + t;
    const int v = (i < n) ? cnt[i] : 0;
    if (i < n) dinv[i] = rsqrtf((float)v + 1.0f);  // +1 self loop
    s[t] = v;
    __syncthreads();
    for (int off = 1; off < 256; off <<= 1) {
        int add = (t >= off) ? s[t - off] : 0;
        __syncthreads();
        s[t] += add;
        __syncthreads();
    }
    if (i < n) ex[i] = s[t] - v;
    if (t == 255) blk_sum[blockIdx.x] = s[255];
}

// Adds global block offset (block-local reduction of blk_sum) + resets cnt.
__global__ __launch_bounds__(256) void k_scan_add(int* __restrict__ row_ptr,
                                                  const int* __restrict__ blk_sum,
                                                  int* __restrict__ cnt, int n, int e) {
    __shared__ int s[256];
    const int t = threadIdx.x;
    const int b = blockIdx.x;
    s[t] = (t < b) ? blk_sum[t] : 0;   // nb <= 256 guaranteed
    __syncthreads();
    for (int off = 128; off > 0; off >>= 1) {
        if (t < off) s[t] += s[t + off];
        __syncthreads();
    }
    const int offset = s[0];
    const int i = b * 256 + t;
    if (i < n) { row_ptr[i] += offset; cnt[i] = 0; }  // cnt reset -> fill cursor
    if (i == 0) row_ptr[n] = e;
}

// Fill interleaved CSR: csr[pos] = {src, dinv[src]*dinv[dst]} — one 8B store per edge.
__global__ void k_fill(const int* __restrict__ src, const int* __restrict__ dst,
                       const int* __restrict__ row_ptr, int* __restrict__ cursor,
                       int2* __restrict__ csr, const float* __restrict__ dinv, int e) {
    int i = blockIdx.x * blockDim.x + threadIdx.x;
    if (i < e) {
        const int d = dst[i];
        const int s = src[i];
        const int pos = row_ptr[d] + atomicAdd(&cursor[d], 1);
        csr[pos] = make_int2(s, __float_as_int(dinv[s] * dinv[d]));
    }
}

// ---------------- all conversions + buffer zeroing in one dispatch ----------------
__global__ void k_conv(const float* __restrict__ x, unsigned short* __restrict__ xb,
                       const float* __restrict__ W1, unsigned short* __restrict__ Wt1,
                       const float* __restrict__ W2, unsigned short* __restrict__ Wt2,
                       int* __restrict__ cnt, float* __restrict__ pooled,
                       int nx4, int n) {
    const int id = blockIdx.x * 256 + threadIdx.x;
    if (id < n) cnt[id] = 0;
    if (id < 128 * HID) pooled[id] = 0.0f;
    if (id < nx4) {
        const float4 v = *(const float4*)(x + (size_t)id * 4);
        uint2 o;
        o.x = (unsigned)f2bf(v.x) | ((unsigned)f2bf(v.y) << 16);
        o.y = (unsigned)f2bf(v.z) | ((unsigned)f2bf(v.w) << 16);
        *(uint2*)(xb + (size_t)id * 4) = o;
        return;
    }
    const int id2 = id - nx4;
    if (id2 < INC * HID) {
        const int nn = id2 / INC;
        const int kk = id2 - nn * INC;
        Wt1[id2] = f2bf(W1[kk * HID + nn]);
        return;
    }
    const int id3 = id2 - INC * HID;
    if (id3 < HID * HID) {
        const int nn = id3 / HID;
        const int kk = id3 - nn * HID;
        Wt2[id3] = f2bf(W2[kk * HID + nn]);
    }
}

// ---------------- pull-mode aggregation (WPN waves per node, 128 ch each) ----------------
// Wave (v, half) computes channels [half*128, half*128+128):
//   out[v] = dinv[v]^2*h[v] + sum_in nrm[i]*h[csr[i].x]
// Lane holds 2 bf16 (uint); each row gather = 64 lanes x 4B = 256B contiguous.
// WPN=2 doubles resident waves (and outstanding misses) for CH=256 without VGPR growth;
// cost: edge stream walked WPN times (VALUBusy has headroom).
template <int CH, int WPN>
__global__ __launch_bounds__(256) void k_agg(const unsigned short* __restrict__ h,
                                             const int* __restrict__ row_ptr,
                                             const int2* __restrict__ csr,
                                             const float* __restrict__ dinv,
                                             unsigned short* __restrict__ out, int n) {
    static_assert(CH == WPN * 128, "lane holds 2 bf16");
    const int wid = (blockIdx.x * 256 + threadIdx.x) >> 6;
    const int lane = threadIdx.x & 63;
    const int v = wid / WPN;
    const int half = (WPN == 1) ? 0 : (wid & (WPN - 1));
    if (v >= n) return;
    const float dv = dinv[v];
    const unsigned short* hl = h + half * 128 + lane * 2;

    float acc[2];
    {
        const uint u = *(const uint*)(hl + (size_t)v * CH);
        const float s2 = dv * dv;
        acc[0] = s2 * __uint_as_float(u << 16);
        acc[1] = s2 * __uint_as_float(u & 0xFFFF0000u);
    }

    const int beg = row_ptr[v];
    const int end = row_ptr[v + 1];
    int i = beg;
    for (; i + 4 <= end; i += 4) {  // 4 gathers in flight
        const int2 p0 = csr[i];
        const int2 p1 = csr[i + 1];
        const int2 p2 = csr[i + 2];
        const int2 p3 = csr[i + 3];
        const uint r0 = *(const uint*)(hl + (size_t)p0.x * CH);
        const uint r1 = *(const uint*)(hl + (size_t)p1.x * CH);
        const uint r2 = *(const uint*)(hl + (size_t)p2.x * CH);
        const uint r3 = *(const uint*)(hl + (size_t)p3.x * CH);
        bfacc2(acc, r0, __int_as_float(p0.y));
        bfacc2(acc, r1, __int_as_float(p1.y));
        bfacc2(acc, r2, __int_as_float(p2.y));
        bfacc2(acc, r3, __int_as_float(p3.y));
    }
    for (; i < end; ++i) {
        const int2 p0 = csr[i];
        const uint r0 = *(const uint*)(hl + (size_t)p0.x * CH);
        bfacc2(acc, r0, __int_as_float(p0.y));
    }

    const uint o = (unsigned)f2bf(acc[0]) | ((unsigned)f2bf(acc[1]) << 16);
    *(uint*)(out + (size_t)v * CH + half * 128 + lane * 2) = o;
}

// ---------------- MFMA GEMM: out = A[M,K] @ W[K,256] + b, with optional fused relu+pool ----------------
// Block = 4 waves, M-tile = 32. Wave w owns N-cols [64w, 64w+64) as 2x4 mfma_f32_16x16x32_bf16.
// POOL: relu'd rows segment-summed over sorted batch ids, atomicAdd into pooled_sum (L2-resident).
template <int K, bool RELU, bool POOL, typename OT>
__global__ __launch_bounds__(256) void k_gemm_mfma(const unsigned short* __restrict__ A,
                                                   const unsigned short* __restrict__ Wt,
                                                   const float* __restrict__ bias,
                                                   OT* __restrict__ out,
                                                   const int* __restrict__ batch,
                                                   float* __restrict__ pooled_sum, int M) {
    constexpr int LDA = K + 8;  // +16B pad: breaks power-of-2 LDS stride
    __shared__ unsigned short sA[32 * LDA];
    __shared__ int s_batch[32];
    const int t = threadIdx.x;
    const int row0 = blockIdx.x * 32;

    // stage 32 x K bf16 tile into LDS (16B chunks); zero-fill rows >= M
    {
        const int r = t >> 3;                // 0..31
        const int c0 = (t & 7) * (K / 8);    // K=128 -> 16 cols, K=256 -> 32 cols
        unsigned short* dstp = &sA[r * LDA + c0];
        if (row0 + r < M) {
            const unsigned short* srcp = A + (size_t)(row0 + r) * K + c0;
#pragma unroll
            for (int j = 0; j < K / 8; j += 8)
                *(uint4*)(dstp + j) = *(const uint4*)(srcp + j);
        } else {
            const uint4 z = {0, 0, 0, 0};
#pragma unroll
            for (int j = 0; j < K / 8; j += 8) *(uint4*)(dstp + j) = z;
        }
        if constexpr (POOL) {
            if (t < 32) s_batch[t] = (row0 + t < M) ? batch[row0 + t] : -1;
        }
    }
    __syncthreads();

    const int wv = t >> 6;
    const int lane = t & 63;
    const int m16 = lane & 15;
    const int quad = lane >> 4;

    floatx4 acc[2][4];
#pragma unroll
    for (int h2 = 0; h2 < 2; ++h2)
#pragma unroll
        for (int j = 0; j < 4; ++j) acc[h2][j] = (floatx4){0.f, 0.f, 0.f, 0.f};

    const unsigned short* ap0 = &sA[m16 * LDA + quad * 8];
    const unsigned short* ap1 = &sA[(16 + m16) * LDA + quad * 8];
    const unsigned short* bp = Wt + (size_t)(wv * 64 + m16) * K + quad * 8;

#pragma unroll
    for (int k0 = 0; k0 < K; k0 += 32) {
        const short8 a0 = *(const short8*)(ap0 + k0);
        const short8 a1 = *(const short8*)(ap1 + k0);
        const short8 b0 = *(const short8*)(bp + 0 * 16 * K + k0);
        const short8 b1 = *(const short8*)(bp + 1 * 16 * K + k0);
        const short8 b2 = *(const short8*)(bp + 2 * 16 * K + k0);
        const short8 b3 = *(const short8*)(bp + 3 * 16 * K + k0);
        acc[0][0] = __builtin_amdgcn_mfma_f32_16x16x32_bf16(a0, b0, acc[0][0], 0, 0, 0);
        acc[0][1] = __builtin_amdgcn_mfma_f32_16x16x32_bf16(a0, b1, acc[0][1], 0, 0, 0);
        acc[0][2] = __builtin_amdgcn_mfma_f32_16x16x32_bf16(a0, b2, acc[0][2], 0, 0, 0);
        acc[0][3] = __builtin_amdgcn_mfma_f32_16x16x32_bf16(a0, b3, acc[0][3], 0, 0, 0);
        acc[1][0] = __builtin_amdgcn_mfma_f32_16x16x32_bf16(a1, b0, acc[1][0], 0, 0, 0);
        acc[1][1] = __builtin_amdgcn_mfma_f32_16x16x32_bf16(a1, b1, acc[1][1], 0, 0, 0);
        acc[1][2] = __builtin_amdgcn_mfma_f32_16x16x32_bf16(a1, b2, acc[1][2], 0, 0, 0);
        acc[1][3] = __builtin_amdgcn_mfma_f32_16x16x32_bf16(a1, b3, acc[1][3], 0, 0, 0);
    }

    // D layout: col = lane&15 (N), row = quad*4 + reg (M within subtile)
    const int nbase = wv * 64 + m16;
    const float bb0 = bias[nbase + 0];
    const float bb1 = bias[nbase + 16];
    const float bb2 = bias[nbase + 32];
    const float bb3 = bias[nbase + 48];

    if constexpr (POOL) {
        float ps0 = 0.f, ps1 = 0.f, ps2 = 0.f, ps3 = 0.f;
        int gcur = -1;
#pragma unroll
        for (int h2 = 0; h2 < 2; ++h2) {
#pragma unroll
            for (int j = 0; j < 4; ++j) {
                const int rl = h2 * 16 + quad * 4 + j;
                const int g = s_batch[rl];
                if (g < 0) continue;
                if (g != gcur) {
                    if (gcur >= 0) {
                        float* pp = pooled_sum + gcur * HID + nbase;
                        atomicAdd(pp + 0, ps0);
                        atomicAdd(pp + 16, ps1);
                        atomicAdd(pp + 32, ps2);
                        atomicAdd(pp + 48, ps3);
                    }
                    ps0 = ps1 = ps2 = ps3 = 0.f;
                    gcur = g;
                }
                ps0 += fmaxf(acc[h2][0][j] + bb0, 0.f);
                ps1 += fmaxf(acc[h2][1][j] + bb1, 0.f);
                ps2 += fmaxf(acc[h2][2][j] + bb2, 0.f);
                ps3 += fmaxf(acc[h2][3][j] + bb3, 0.f);
            }
        }
        if (gcur >= 0) {
            float* pp = pooled_sum + gcur * HID + nbase;
            atomicAdd(pp + 0, ps0);
            atomicAdd(pp + 16, ps1);
            atomicAdd(pp + 32, ps2);
            atomicAdd(pp + 48, ps3);
        }
    } else {
#pragma unroll
        for (int h2 = 0; h2 < 2; ++h2) {
#pragma unroll
            for (int j = 0; j < 4; ++j) {
                const int row = row0 + h2 * 16 + quad * 4 + j;
                if (row >= M) continue;
                float v0 = acc[h2][0][j] + bb0;
                float v1 = acc[h2][1][j] + bb1;
                float v2 = acc[h2][2][j] + bb2;
                float v3 = acc[h2][3][j] + bb3;
                if constexpr (RELU) {
                    v0 = fmaxf(v0, 0.f); v1 = fmaxf(v1, 0.f);
                    v2 = fmaxf(v2, 0.f); v3 = fmaxf(v3, 0.f);
                }
                out[(size_t)row * HID + nbase + 0]  = (OT)f2bf(v0);
                out[(size_t)row * HID + nbase + 16] = (OT)f2bf(v1);
                out[(size_t)row * HID + nbase + 32] = (OT)f2bf(v2);
                out[(size_t)row * HID + nbase + 48] = (OT)f2bf(v3);
            }
        }
    }
}

// ---------------- final FC with fused mean: out[g] = (sum[g] @ Wfc)/cnt + bfc ----------------
__global__ void k_fc(const float* __restrict__ pooled_sum, const int* __restrict__ batch,
                     const float* __restrict__ W, const float* __restrict__ b,
                     float* __restrict__ out, int n) {
    const int g = blockIdx.x;
    const int c = threadIdx.x;  // 128
    int a = 0, hi = n;
    while (a < hi) { int m = (a + hi) >> 1; if (batch[m] < g) a = m + 1; else hi = m; }
    const int start = a;
    hi = n;
    while (a < hi) { int m = (a + hi) >> 1; if (batch[m] < g + 1) a = m + 1; else hi = m; }
    const float cnt = (float)(a - start);

    float acc = 0.0f;
    const float* p = pooled_sum + g * HID;
    for (int k = 0; k < HID; ++k) acc += p[k] * W[k * OUTC + c];
    out[g * OUTC + c] = acc / fmaxf(cnt, 1.0f) + b[c];
}

extern "C" void kernel_launch(void* const* d_in, const int* in_sizes, int n_in,
                              void* d_out, int out_size, void* d_ws, size_t ws_size,
                              hipStream_t stream) {
    const float* x   = (const float*)d_in[0];
    const int*   ei  = (const int*)d_in[1];
    const int*   bat = (const int*)d_in[2];
    const float* W1  = (const float*)d_in[3];
    const float* b1  = (const float*)d_in[4];
    const float* W2  = (const float*)d_in[5];
    const float* b2  = (const float*)d_in[6];
    const float* Wfc = (const float*)d_in[7];
    const float* bfc = (const float*)d_in[8];
    float* out = (float*)d_out;

    const int n = in_sizes[2];       // 50000 nodes
    const int e = in_sizes[1] / 2;   // 800000 edges
    const int* src = ei;
    const int* dst = ei + e;
    const int nb = (n + 255) / 256;  // scan blocks (196 <= 256)

    // Workspace layout (each buffer 256B-aligned)
    size_t off = 0;
    auto alloc = [&](size_t bytes) {
        char* p = (char*)d_ws + off;
        off += (bytes + 255) & ~(size_t)255;
        return p;
    };
    int*   cnt     = (int*)alloc((size_t)n * 4);
    int*   row_ptr = (int*)alloc((size_t)(n + 1) * 4);
    int*   blk_sum = (int*)alloc(512 * 4);
    int2*  csr     = (int2*)alloc((size_t)e * 8);
    float* dinv    = (float*)alloc((size_t)n * 4);
    unsigned short* Wt1 = (unsigned short*)alloc((size_t)INC * HID * 2);
    unsigned short* Wt2 = (unsigned short*)alloc((size_t)HID * HID * 2);
    unsigned short* R1  = (unsigned short*)alloc((size_t)n * HID * 2);  // xbf, later agg1
    unsigned short* R2  = (unsigned short*)alloc((size_t)n * INC * 2);  // agg0
    unsigned short* R3  = (unsigned short*)alloc((size_t)n * HID * 2);  // h1
    float* pooled = (float*)alloc((size_t)128 * HID * 4);               // fp32 sums

    const int TB = 256;
    const int nx4 = n * INC / 4;

    // All conversions + cnt/pooled zeroing in one dispatch (stream-ordered before consumers)
    k_conv<<<(nx4 + INC * HID + HID * HID + TB - 1) / TB, TB, 0, stream>>>(
        x, R1, W1, Wt1, W2, Wt2, cnt, pooled, nx4, n);

    // CSR build (dinv fused into scan_local; edge norms interleaved in fill)
    k_hist<<<(e + TB - 1) / TB, TB, 0, stream>>>(dst, cnt, e);
    k_scan_local<<<nb, TB, 0, stream>>>(cnt, row_ptr, blk_sum, dinv, n);
    k_scan_add<<<nb, TB, 0, stream>>>(row_ptr, blk_sum, cnt, n, e);
    k_fill<<<(e + TB - 1) / TB, TB, 0, stream>>>(src, dst, row_ptr, cnt, csr, dinv, e);

    const int gemm_blocks = (n + 31) / 32;

    // Layer 1 (linearity): agg0 = A.x (1 wave/node); h1 = relu(agg0 @ W1 + b1)
    k_agg<INC, 1><<<(n + 3) / 4, TB, 0, stream>>>(R1, row_ptr, csr, dinv, R2, n);
    k_gemm_mfma<INC, true, false, unsigned short><<<gemm_blocks, TB, 0, stream>>>(
        R2, Wt1, b1, R3, nullptr, nullptr, n);

    // Layer 2: agg1 = A.h1 (2 waves/node: doubles outstanding misses); fused conv2+relu+pool
    k_agg<HID, 2><<<(2 * n + 3) / 4, TB, 0, stream>>>(R3, row_ptr, csr, dinv, R1, n);
    k_gemm_mfma<HID, true, true, float><<<gemm_blocks, TB, 0, stream>>>(
        R1, Wt2, b2, (float*)nullptr, bat, pooled, n);

    // FC with fused mean
    k_fc<<<128, 128, 0, stream>>>(pooled, bat, Wfc, bfc, out, n);
}

// Round 15
// 345.950 us; speedup vs baseline: 1.0313x; 1.0313x over previous
//
#include <hip/hip_runtime.h>
#include <type_traits>

// Problem constants (fixed by the reference)
#define HID 256
#define INC 128
#define OUTC 128

typedef __attribute__((ext_vector_type(8))) short short8;     // 8 bf16 = 4 VGPRs (MFMA A/B frag)
typedef __attribute__((ext_vector_type(4))) float floatx4;    // MFMA C/D frag

__device__ __forceinline__ unsigned short f2bf(float f) {
    unsigned int u = __float_as_uint(f);
    unsigned int r = (u + 0x7FFFu + ((u >> 16) & 1u)) >> 16;  // RNE
    return (unsigned short)r;
}

__device__ __forceinline__ void bfacc2(float* a, uint u, float nr) {
    a[0] = fmaf(nr, __uint_as_float(u << 16), a[0]);
    a[1] = fmaf(nr, __uint_as_float(u & 0xFFFF0000u), a[1]);
}

// ---------------- CSR build ----------------
__global__ void k_hist(const int* __restrict__ dst, int* __restrict__ cnt, int e) {
    int i = blockIdx.x * blockDim.x + threadIdx.x;
    if (i < e) atomicAdd(&cnt[dst[i]], 1);
}

// Local scan (per 256-block) + dinv computed from pre-scan counts (fused).
__global__ __launch_bounds__(256) void k_scan_local(const int* __restrict__ cnt,
                                                    int* __restrict__ ex, int* __restrict__ blk_sum,
                                                    float* __restrict__ dinv, int n) {
    __shared__ int s[256];
    const int t = threadIdx.x;
    const int i = blockIdx.x * 256 + t;
    const int v = (i < n) ? cnt[i] : 0;
    if (i < n) dinv[i] = rsqrtf((float)v + 1.0f);  // +1 self loop
    s[t] = v;
    __syncthreads();
    for (int off = 1; off < 256; off <<= 1) {
        int add = (t >= off) ? s[t - off] : 0;
        __syncthreads();
        s[t] += add;
        __syncthreads();
    }
    if (i < n) ex[i] = s[t] - v;
    if (t == 255) blk_sum[blockIdx.x] = s[255];
}

// Adds global block offset (block-local reduction of blk_sum) + resets cnt.
__global__ __launch_bounds__(256) void k_scan_add(int* __restrict__ row_ptr,
                                                  const int* __restrict__ blk_sum,
                                                  int* __restrict__ cnt, int n, int e) {
    __shared__ int s[256];
    const int t = threadIdx.x;
    const int b = blockIdx.x;
    s[t] = (t < b) ? blk_sum[t] : 0;   // nb <= 256 guaranteed
    __syncthreads();
    for (int off = 128; off > 0; off >>= 1) {
        if (t < off) s[t] += s[t + off];
        __syncthreads();
    }
    const int offset = s[0];
    const int i = b * 256 + t;
    if (i < n) { row_ptr[i] += offset; cnt[i] = 0; }  // cnt reset -> fill cursor
    if (i == 0) row_ptr[n] = e;
}

// Fill interleaved CSR: csr[pos] = {src, dinv[src]*dinv[dst]} — one 8B store per edge,
// and the aggregate reads index+norm with a single 8B load.
__global__ void k_fill(const int* __restrict__ src, const int* __restrict__ dst,
                       const int* __restrict__ row_ptr, int* __restrict__ cursor,
                       int2* __restrict__ csr, const float* __restrict__ dinv, int e) {
    int i = blockIdx.x * blockDim.x + threadIdx.x;
    if (i < e) {
        const int d = dst[i];
        const int s = src[i];
        const int pos = row_ptr[d] + atomicAdd(&cursor[d], 1);
        csr[pos] = make_int2(s, __float_as_int(dinv[s] * dinv[d]));
    }
}

// ---------------- all conversions + buffer zeroing in one dispatch ----------------
// x fp32->bf16 (4ch/thread), W1/W2 transpose+convert, cnt=0, pooled=0.
__global__ void k_conv(const float* __restrict__ x, unsigned short* __restrict__ xb,
                       const float* __restrict__ W1, unsigned short* __restrict__ Wt1,
                       const float* __restrict__ W2, unsigned short* __restrict__ Wt2,
                       int* __restrict__ cnt, float* __restrict__ pooled,
                       int nx4, int n) {
    const int id = blockIdx.x * 256 + threadIdx.x;
    if (id < n) cnt[id] = 0;
    if (id < 128 * HID) pooled[id] = 0.0f;
    if (id < nx4) {
        const float4 v = *(const float4*)(x + (size_t)id * 4);
        uint2 o;
        o.x = (unsigned)f2bf(v.x) | ((unsigned)f2bf(v.y) << 16);
        o.y = (unsigned)f2bf(v.z) | ((unsigned)f2bf(v.w) << 16);
        *(uint2*)(xb + (size_t)id * 4) = o;
        return;
    }
    const int id2 = id - nx4;
    if (id2 < INC * HID) {
        const int nn = id2 / INC;
        const int kk = id2 - nn * INC;
        Wt1[id2] = f2bf(W1[kk * HID + nn]);
        return;
    }
    const int id3 = id2 - INC * HID;
    if (id3 < HID * HID) {
        const int nn = id3 / HID;
        const int kk = id3 - nn * HID;
        Wt2[id3] = f2bf(W2[kk * HID + nn]);
    }
}

// ---------------- pull-mode aggregation (row-major, 4-edge ILP, interleaved CSR) ----------------
// One wave per node v: out[v] = dinv[v]^2*h[v] + sum_in nrm[i]*h[csr[i].x]
// CH=128 -> uint/lane (2ch), CH=256 -> uint2/lane (4ch). Row gather = 64 lanes coalesced.
template <int CH>
__global__ __launch_bounds__(256) void k_agg(const unsigned short* __restrict__ h,
                                             const int* __restrict__ row_ptr,
                                             const int2* __restrict__ csr,
                                             const float* __restrict__ dinv,
                                             unsigned short* __restrict__ out, int n) {
    constexpr int CPL = CH / 64;  // bf16 per lane: 2 or 4
    using VT = std::conditional_t<CPL == 2, uint, uint2>;
    const int v = (blockIdx.x * 256 + threadIdx.x) >> 6;
    const int lane = threadIdx.x & 63;
    if (v >= n) return;
    const float dv = dinv[v];
    const unsigned short* hl = h + lane * CPL;

    float acc[CPL];
    {
        const VT u = *(const VT*)(hl + (size_t)v * CH);
        const float s2 = dv * dv;
        if constexpr (CPL == 2) {
            acc[0] = s2 * __uint_as_float(((uint)u) << 16);
            acc[1] = s2 * __uint_as_float(((uint)u) & 0xFFFF0000u);
        } else {
            const uint2 w = (uint2)u;
            acc[0] = s2 * __uint_as_float(w.x << 16);
            acc[1] = s2 * __uint_as_float(w.x & 0xFFFF0000u);
            acc[2] = s2 * __uint_as_float(w.y << 16);
            acc[3] = s2 * __uint_as_float(w.y & 0xFFFF0000u);
        }
    }

    const int beg = row_ptr[v];
    const int end = row_ptr[v + 1];
    int i = beg;
    for (; i + 4 <= end; i += 4) {  // 4 gathers in flight
        const int2 p0 = csr[i];
        const int2 p1 = csr[i + 1];
        const int2 p2 = csr[i + 2];
        const int2 p3 = csr[i + 3];
        const float n0 = __int_as_float(p0.y);
        const float n1 = __int_as_float(p1.y);
        const float n2 = __int_as_float(p2.y);
        const float n3 = __int_as_float(p3.y);
        const VT r0 = *(const VT*)(hl + (size_t)p0.x * CH);
        const VT r1 = *(const VT*)(hl + (size_t)p1.x * CH);
        const VT r2 = *(const VT*)(hl + (size_t)p2.x * CH);
        const VT r3 = *(const VT*)(hl + (size_t)p3.x * CH);
        if constexpr (CPL == 2) {
            bfacc2(acc, (uint)r0, n0);
            bfacc2(acc, (uint)r1, n1);
            bfacc2(acc, (uint)r2, n2);
            bfacc2(acc, (uint)r3, n3);
        } else {
            const uint2 w0 = (uint2)r0, w1 = (uint2)r1, w2 = (uint2)r2, w3 = (uint2)r3;
            bfacc2(acc, w0.x, n0); bfacc2(acc + 2, w0.y, n0);
            bfacc2(acc, w1.x, n1); bfacc2(acc + 2, w1.y, n1);
            bfacc2(acc, w2.x, n2); bfacc2(acc + 2, w2.y, n2);
            bfacc2(acc, w3.x, n3); bfacc2(acc + 2, w3.y, n3);
        }
    }
    for (; i < end; ++i) {
        const int2 p0 = csr[i];
        const float n0 = __int_as_float(p0.y);
        const VT r0 = *(const VT*)(hl + (size_t)p0.x * CH);
        if constexpr (CPL == 2) {
            bfacc2(acc, (uint)r0, n0);
        } else {
            const uint2 w0 = (uint2)r0;
            bfacc2(acc, w0.x, n0); bfacc2(acc + 2, w0.y, n0);
        }
    }

    if constexpr (CPL == 2) {
        uint o = (unsigned)f2bf(acc[0]) | ((unsigned)f2bf(acc[1]) << 16);
        *(uint*)(out + (size_t)v * CH + lane * CPL) = o;
    } else {
        uint2 o;
        o.x = (unsigned)f2bf(acc[0]) | ((unsigned)f2bf(acc[1]) << 16);
        o.y = (unsigned)f2bf(acc[2]) | ((unsigned)f2bf(acc[3]) << 16);
        *(uint2*)(out + (size_t)v * CH + lane * CPL) = o;
    }
}

// ---------------- MFMA GEMM: out = A[M,K] @ W[K,256] + b, with optional fused relu+pool ----------------
// Block = 4 waves, M-tile = 32. Wave w owns N-cols [64w, 64w+64) as 2x4 mfma_f32_16x16x32_bf16.
// POOL: relu'd rows segment-summed over sorted batch ids, atomicAdd into pooled_sum (L2-resident).
template <int K, bool RELU, bool POOL, typename OT>
__global__ __launch_bounds__(256) void k_gemm_mfma(const unsigned short* __restrict__ A,
                                                   const unsigned short* __restrict__ Wt,
                                                   const float* __restrict__ bias,
                                                   OT* __restrict__ out,
                                                   const int* __restrict__ batch,
                                                   float* __restrict__ pooled_sum, int M) {
    constexpr int LDA = K + 8;  // +16B pad: breaks power-of-2 LDS stride
    __shared__ unsigned short sA[32 * LDA];
    __shared__ int s_batch[32];
    const int t = threadIdx.x;
    const int row0 = blockIdx.x * 32;

    // stage 32 x K bf16 tile into LDS (16B chunks); zero-fill rows >= M
    {
        const int r = t >> 3;                // 0..31
        const int c0 = (t & 7) * (K / 8);    // K=128 -> 16 cols, K=256 -> 32 cols
        unsigned short* dstp = &sA[r * LDA + c0];
        if (row0 + r < M) {
            const unsigned short* srcp = A + (size_t)(row0 + r) * K + c0;
#pragma unroll
            for (int j = 0; j < K / 8; j += 8)
                *(uint4*)(dstp + j) = *(const uint4*)(srcp + j);
        } else {
            const uint4 z = {0, 0, 0, 0};
#pragma unroll
            for (int j = 0; j < K / 8; j += 8) *(uint4*)(dstp + j) = z;
        }
        if constexpr (POOL) {
            if (t < 32) s_batch[t] = (row0 + t < M) ? batch[row0 + t] : -1;
        }
    }
    __syncthreads();

    const int wv = t >> 6;
    const int lane = t & 63;
    const int m16 = lane & 15;
    const int quad = lane >> 4;

    floatx4 acc[2][4];
#pragma unroll
    for (int h2 = 0; h2 < 2; ++h2)
#pragma unroll
        for (int j = 0; j < 4; ++j) acc[h2][j] = (floatx4){0.f, 0.f, 0.f, 0.f};

    const unsigned short* ap0 = &sA[m16 * LDA + quad * 8];
    const unsigned short* ap1 = &sA[(16 + m16) * LDA + quad * 8];
    const unsigned short* bp = Wt + (size_t)(wv * 64 + m16) * K + quad * 8;

#pragma unroll
    for (int k0 = 0; k0 < K; k0 += 32) {
        const short8 a0 = *(const short8*)(ap0 + k0);
        const short8 a1 = *(const short8*)(ap1 + k0);
        const short8 b0 = *(const short8*)(bp + 0 * 16 * K + k0);
        const short8 b1 = *(const short8*)(bp + 1 * 16 * K + k0);
        const short8 b2 = *(const short8*)(bp + 2 * 16 * K + k0);
        const short8 b3 = *(const short8*)(bp + 3 * 16 * K + k0);
        acc[0][0] = __builtin_amdgcn_mfma_f32_16x16x32_bf16(a0, b0, acc[0][0], 0, 0, 0);
        acc[0][1] = __builtin_amdgcn_mfma_f32_16x16x32_bf16(a0, b1, acc[0][1], 0, 0, 0);
        acc[0][2] = __builtin_amdgcn_mfma_f32_16x16x32_bf16(a0, b2, acc[0][2], 0, 0, 0);
        acc[0][3] = __builtin_amdgcn_mfma_f32_16x16x32_bf16(a0, b3, acc[0][3], 0, 0, 0);
        acc[1][0] = __builtin_amdgcn_mfma_f32_16x16x32_bf16(a1, b0, acc[1][0], 0, 0, 0);
        acc[1][1] = __builtin_amdgcn_mfma_f32_16x16x32_bf16(a1, b1, acc[1][1], 0, 0, 0);
        acc[1][2] = __builtin_amdgcn_mfma_f32_16x16x32_bf16(a1, b2, acc[1][2], 0, 0, 0);
        acc[1][3] = __builtin_amdgcn_mfma_f32_16x16x32_bf16(a1, b3, acc[1][3], 0, 0, 0);
    }

    // D layout: col = lane&15 (N), row = quad*4 + reg (M within subtile)
    const int nbase = wv * 64 + m16;
    const float bb0 = bias[nbase + 0];
    const float bb1 = bias[nbase + 16];
    const float bb2 = bias[nbase + 32];
    const float bb3 = bias[nbase + 48];

    if constexpr (POOL) {
        float ps0 = 0.f, ps1 = 0.f, ps2 = 0.f, ps3 = 0.f;
        int gcur = -1;
#pragma unroll
        for (int h2 = 0; h2 < 2; ++h2) {
#pragma unroll
            for (int j = 0; j < 4; ++j) {
                const int rl = h2 * 16 + quad * 4 + j;
                const int g = s_batch[rl];
                if (g < 0) continue;
                if (g != gcur) {
                    if (gcur >= 0) {
                        float* pp = pooled_sum + gcur * HID + nbase;
                        atomicAdd(pp + 0, ps0);
                        atomicAdd(pp + 16, ps1);
                        atomicAdd(pp + 32, ps2);
                        atomicAdd(pp + 48, ps3);
                    }
                    ps0 = ps1 = ps2 = ps3 = 0.f;
                    gcur = g;
                }
                ps0 += fmaxf(acc[h2][0][j] + bb0, 0.f);
                ps1 += fmaxf(acc[h2][1][j] + bb1, 0.f);
                ps2 += fmaxf(acc[h2][2][j] + bb2, 0.f);
                ps3 += fmaxf(acc[h2][3][j] + bb3, 0.f);
            }
        }
        if (gcur >= 0) {
            float* pp = pooled_sum + gcur * HID + nbase;
            atomicAdd(pp + 0, ps0);
            atomicAdd(pp + 16, ps1);
            atomicAdd(pp + 32, ps2);
            atomicAdd(pp + 48, ps3);
        }
    } else {
#pragma unroll
        for (int h2 = 0; h2 < 2; ++h2) {
#pragma unroll
            for (int j = 0; j < 4; ++j) {
                const int row = row0 + h2 * 16 + quad * 4 + j;
                if (row >= M) continue;
                float v0 = acc[h2][0][j] + bb0;
                float v1 = acc[h2][1][j] + bb1;
                float v2 = acc[h2][2][j] + bb2;
                float v3 = acc[h2][3][j] + bb3;
                if constexpr (RELU) {
                    v0 = fmaxf(v0, 0.f); v1 = fmaxf(v1, 0.f);
                    v2 = fmaxf(v2, 0.f); v3 = fmaxf(v3, 0.f);
                }
                out[(size_t)row * HID + nbase + 0]  = (OT)f2bf(v0);
                out[(size_t)row * HID + nbase + 16] = (OT)f2bf(v1);
                out[(size_t)row * HID + nbase + 32] = (OT)f2bf(v2);
                out[(size_t)row * HID + nbase + 48] = (OT)f2bf(v3);
            }
        }
    }
}

// ---------------- final FC with fused mean: out[g] = (sum[g] @ Wfc)/cnt + bfc ----------------
__global__ void k_fc(const float* __restrict__ pooled_sum, const int* __restrict__ batch,
                     const float* __restrict__ W, const float* __restrict__ b,
                     float* __restrict__ out, int n) {
    const int g = blockIdx.x;
    const int c = threadIdx.x;  // 128
    int a = 0, hi = n;
    while (a < hi) { int m = (a + hi) >> 1; if (batch[m] < g) a = m + 1; else hi = m; }
    const int start = a;
    hi = n;
    while (a < hi) { int m = (a + hi) >> 1; if (batch[m] < g + 1) a = m + 1; else hi = m; }
    const float cnt = (float)(a - start);

    float acc = 0.0f;
    const float* p = pooled_sum + g * HID;
    for (int k = 0; k < HID; ++k) acc += p[k] * W[k * OUTC + c];
    out[g * OUTC + c] = acc / fmaxf(cnt, 1.0f) + b[c];
}

extern "C" void kernel_launch(void* const* d_in, const int* in_sizes, int n_in,
                              void* d_out, int out_size, void* d_ws, size_t ws_size,
                              hipStream_t stream) {
    const float* x   = (const float*)d_in[0];
    const int*   ei  = (const int*)d_in[1];
    const int*   bat = (const int*)d_in[2];
    const float* W1  = (const float*)d_in[3];
    const float* b1  = (const float*)d_in[4];
    const float* W2  = (const float*)d_in[5];
    const float* b2  = (const float*)d_in[6];
    const float* Wfc = (const float*)d_in[7];
    const float* bfc = (const float*)d_in[8];
    float* out = (float*)d_out;

    const int n = in_sizes[2];       // 50000 nodes
    const int e = in_sizes[1] / 2;   // 800000 edges
    const int* src = ei;
    const int* dst = ei + e;
    const int nb = (n + 255) / 256;  // scan blocks (196 <= 256)

    // Workspace layout (each buffer 256B-aligned)
    size_t off = 0;
    auto alloc = [&](size_t bytes) {
        char* p = (char*)d_ws + off;
        off += (bytes + 255) & ~(size_t)255;
        return p;
    };
    int*   cnt     = (int*)alloc((size_t)n * 4);
    int*   row_ptr = (int*)alloc((size_t)(n + 1) * 4);
    int*   blk_sum = (int*)alloc(512 * 4);
    int2*  csr     = (int2*)alloc((size_t)e * 8);
    float* dinv    = (float*)alloc((size_t)n * 4);
    unsigned short* Wt1 = (unsigned short*)alloc((size_t)INC * HID * 2);
    unsigned short* Wt2 = (unsigned short*)alloc((size_t)HID * HID * 2);
    unsigned short* R1  = (unsigned short*)alloc((size_t)n * HID * 2);  // xbf, later agg1
    unsigned short* R2  = (unsigned short*)alloc((size_t)n * INC * 2);  // agg0
    unsigned short* R3  = (unsigned short*)alloc((size_t)n * HID * 2);  // h1
    float* pooled = (float*)alloc((size_t)128 * HID * 4);               // fp32 sums

    const int TB = 256;
    const int nx4 = n * INC / 4;

    // All conversions + cnt/pooled zeroing in one dispatch (stream-ordered before consumers)
    k_conv<<<(nx4 + INC * HID + HID * HID + TB - 1) / TB, TB, 0, stream>>>(
        x, R1, W1, Wt1, W2, Wt2, cnt, pooled, nx4, n);

    // CSR build (dinv fused into scan_local; edge norms interleaved in fill)
    k_hist<<<(e + TB - 1) / TB, TB, 0, stream>>>(dst, cnt, e);
    k_scan_local<<<nb, TB, 0, stream>>>(cnt, row_ptr, blk_sum, dinv, n);
    k_scan_add<<<nb, TB, 0, stream>>>(row_ptr, blk_sum, cnt, n, e);
    k_fill<<<(e + TB - 1) / TB, TB, 0, stream>>>(src, dst, row_ptr, cnt, csr, dinv, e);

    const int gemm_blocks = (n + 31) / 32;
    const int agg_blocks = (n + 3) / 4;

    // Layer 1 (linearity): agg0 = A.x ; h1 = relu(agg0 @ W1 + b1)
    k_agg<INC><<<agg_blocks, TB, 0, stream>>>(R1, row_ptr, csr, dinv, R2, n);
    k_gemm_mfma<INC, true, false, unsigned short><<<gemm_blocks, TB, 0, stream>>>(
        R2, Wt1, b1, R3, nullptr, nullptr, n);

    // Layer 2: agg1 = A.h1 ; fused conv2 + relu + mean-pool partial sums
    k_agg<HID><<<agg_blocks, TB, 0, stream>>>(R3, row_ptr, csr, dinv, R1, n);
    k_gemm_mfma<HID, true, true, float><<<gemm_blocks, TB, 0, stream>>>(
        R1, Wt2, b2, (float*)nullptr, bat, pooled, n);

    // FC with fused mean
    k_fc<<<128, 128, 0, stream>>>(pooled, bat, Wfc, bfc, out, n);
}